// Round 6
// baseline (704.560 us; speedup 1.0000x reference)
//
#include <hip/hip_runtime.h>

// Problem constants (match reference)
#define BATCH 4
#define SLEN  4096
#define DIMK  4096
#define HD    512
#define RD    64
#define NCOLS 2048          // [kv(1024) | sc(1024)]
#define MROWS (BATCH*SLEN)  // 16384

typedef __attribute__((ext_vector_type(8))) short bf16x8;
typedef __attribute__((ext_vector_type(4))) float f32x4;
typedef unsigned short u16;

// ---------- bf16 helpers ----------
__device__ inline u16 f2b(float f) {
  union { float f; unsigned u; } x; x.f = f;
  unsigned r = (x.u + 0x7fffu + ((x.u >> 16) & 1u)) >> 16;
  return (u16)r;
}
__device__ inline float b2f(u16 u) {
  union { float f; unsigned u; } x; x.u = ((unsigned)u) << 16; return x.f;
}

#define GLL16(gp, lp) __builtin_amdgcn_global_load_lds( \
    (__attribute__((address_space(1))) void*)(gp),      \
    (__attribute__((address_space(3))) void*)(lp), 16, 0, 0)

// ---------- kernel 1: x (f32) -> bf16 ----------
__global__ __launch_bounds__(256) void cvt_x_kernel(const float4* __restrict__ x,
                                                    u16* __restrict__ xb) {
  size_t i = (size_t)blockIdx.x * 256 + threadIdx.x;
  float4 a = x[2 * i], b = x[2 * i + 1];
  bf16x8 v;
  v[0] = (short)f2b(a.x); v[1] = (short)f2b(a.y);
  v[2] = (short)f2b(a.z); v[3] = (short)f2b(a.w);
  v[4] = (short)f2b(b.x); v[5] = (short)f2b(b.y);
  v[6] = (short)f2b(b.z); v[7] = (short)f2b(b.w);
  *(bf16x8*)(xb + i * 8) = v;
}

// ---------- kernel 2: Wt[n][k] = [wkv|wgate][k][n] as bf16 ----------
__global__ __launch_bounds__(256) void build_wt_kernel(const float* __restrict__ wkv,
                                                       const float* __restrict__ wg,
                                                       u16* __restrict__ Wt) {
  __shared__ u16 tile[64][72];
  const int n0 = blockIdx.x * 64;
  const int k0 = blockIdx.y * 64;
  const float* src = (n0 < 1024) ? wkv : wg;
  const int nbase = (n0 < 1024) ? n0 : (n0 - 1024);
  const int t = threadIdx.x;
  const int nn = t & 63, kq = t >> 6;
  #pragma unroll
  for (int j = 0; j < 16; ++j) {
    int k = kq + j * 4;
    float v = src[(size_t)(k0 + k) * 1024 + nbase + nn];
    tile[nn][k] = f2b(v);
  }
  __syncthreads();
  const int kk8 = (t & 7) * 8;
  #pragma unroll
  for (int j = 0; j < 2; ++j) {
    int nn2 = (t >> 3) + j * 32;
    bf16x8 v = *(bf16x8*)&tile[nn2][kk8];
    *(bf16x8*)&Wt[(size_t)(n0 + nn2) * DIMK + k0 + kk8] = v;
  }
}

// ---------- kernel 3: GEMM 256x256, BK=64, dbuf, sub-phase register pipeline ----------
// R4 diagnosis: {reads; BAR; MFMA; BAR} serializes LDS unit vs MFMA pipe
// block-wide (2300 + 2480 cyc/tile). Fix: issue next sub-phase's ds_reads
// BEFORE current MFMA burst; compiler's fine-grained lgkmcnt (m97-verified)
// interleaves them -> LDS runs under MFMA. 2 barriers/K-tile, counted vmcnt(8).
// LDS [buf][kc][row][8] k-chunk-major: GLL-linear AND conflict-free (meas. 0).
__global__ __launch_bounds__(512, 2) void gemm_kernel(const u16* __restrict__ A,
                                                      const u16* __restrict__ Bt,
                                                      u16* __restrict__ C) {
  __shared__ __align__(16) u16 Asm[2][8][256][8];   // 64 KiB
  __shared__ __align__(16) u16 Bsm[2][8][256][8];   // 64 KiB
  const int t = threadIdx.x;
  const int lane = t & 63, wave = t >> 6;

  // XCD chunked swizzle: nwg=512, 64 contiguous logical blocks per XCD.
  const int orig = blockIdx.x;
  const int lid = (orig & 7) * 64 + (orig >> 3);
  const int mt = lid >> 3, nt = lid & 7;            // nt fast: 8 share A panel
  const int m0 = mt * 256, n0 = nt * 256;
  const int wr = wave >> 2, wc = wave & 3;          // 2M x 4N waves

  f32x4 acc[8][4] = {};

  const int rowS = t & 255, kcS = t >> 8;           // kcS in {0,1}
  const u16* gA = A  + (size_t)(m0 + rowS) * DIMK + kcS * 8;
  const u16* gB = Bt + (size_t)(n0 + rowS) * DIMK + kcS * 8;

  // 8 GLL/thread: full K=64 tile for A and B. chunk kc = 2i+kcS.
#define STAGE(buf, tt) do {                                           \
    _Pragma("unroll")                                                 \
    for (int i = 0; i < 4; ++i) {                                     \
      GLL16(gA + (tt) * 64 + i * 16, &Asm[buf][2 * i + kcS][rowS][0]); \
      GLL16(gB + (tt) * 64 + i * 16, &Bsm[buf][2 * i + kcS][rowS][0]); \
    }                                                                 \
  } while (0)

#define MFMA16(mb, AF, BF) do {                                       \
    __builtin_amdgcn_s_setprio(1);                                    \
    _Pragma("unroll")                                                 \
    for (int m = 0; m < 4; ++m) {                                     \
      _Pragma("unroll")                                               \
      for (int n = 0; n < 4; ++n)                                     \
        acc[(mb) + m][n] = __builtin_amdgcn_mfma_f32_16x16x32_bf16(   \
            AF[m], BF[n], acc[(mb) + m][n], 0, 0, 0);                 \
    }                                                                 \
    __builtin_amdgcn_s_setprio(0);                                    \
  } while (0)

#define BAR()    asm volatile("s_barrier" ::: "memory")
#define VMW(n)   asm volatile("s_waitcnt vmcnt(" #n ")" ::: "memory")

  const int fr = lane & 15, fk = lane >> 4;          // fk in 0..3
  const int NT = DIMK / 64;                          // 64 K-tiles

  STAGE(0, 0);

  for (int tt = 0; tt < NT; ++tt) {
    const int c = tt & 1;
    const int t1 = (tt + 1 < NT) ? tt + 1 : NT - 1;  // clamped tail (dead buf)
    STAGE(c ^ 1, t1);                                // issue-early, 8 GLL
    VMW(8);                                          // stage(tt) landed; tt+1 in flight
    BAR();                                           // buffer c visible to all

    bf16x8 af0[4], af1[4], af2[4], af3[4], bf0[4], bf1[4];
    // G0: k-half 0, m 0-3 + B
    #pragma unroll
    for (int m = 0; m < 4; ++m)
      af0[m] = *(const bf16x8*)&Asm[c][fk][wr * 128 + m * 16 + fr][0];
    #pragma unroll
    for (int n = 0; n < 4; ++n)
      bf0[n] = *(const bf16x8*)&Bsm[c][fk][wc * 64 + n * 16 + fr][0];

    // sp0: read G1 (af m4-7 @k0), MFMA G0
    #pragma unroll
    for (int m = 0; m < 4; ++m)
      af1[m] = *(const bf16x8*)&Asm[c][fk][wr * 128 + (m + 4) * 16 + fr][0];
    MFMA16(0, af0, bf0);

    // sp1: read G2 (af m0-3 @k1 + B @k1), MFMA G1
    #pragma unroll
    for (int m = 0; m < 4; ++m)
      af2[m] = *(const bf16x8*)&Asm[c][4 + fk][wr * 128 + m * 16 + fr][0];
    #pragma unroll
    for (int n = 0; n < 4; ++n)
      bf1[n] = *(const bf16x8*)&Bsm[c][4 + fk][wc * 64 + n * 16 + fr][0];
    MFMA16(4, af1, bf0);

    // sp2: read G3 (af m4-7 @k1), MFMA G2
    #pragma unroll
    for (int m = 0; m < 4; ++m)
      af3[m] = *(const bf16x8*)&Asm[c][4 + fk][wr * 128 + (m + 4) * 16 + fr][0];
    MFMA16(0, af2, bf1);

    // sp3: MFMA G3 (compiler drains lgkm before use)
    MFMA16(4, af3, bf1);

    BAR();                                           // all reads of c done -> next
  }                                                  // iter may restage c
  VMW(0);   // no GLL may land in freed LDS after exit
#undef STAGE
#undef MFMA16
#undef BAR
#undef VMW

  // epilogue: C/D layout col=lane&15, row=(lane>>4)*4+j (m89-verified)
  const int fq = lane >> 4;
  #pragma unroll
  for (int m = 0; m < 8; ++m) {
    #pragma unroll
    for (int n = 0; n < 4; ++n) {
      int col = n0 + wc * 64 + n * 16 + fr;
      int rowb = m0 + wr * 128 + m * 16 + fq * 4;
      #pragma unroll
      for (int j = 0; j < 4; ++j)
        C[(size_t)(rowb + j) * NCOLS + col] = f2b(acc[m][n][j]);
    }
  }
}

// ---------- kernel 4: windowed softmax + halves-sum + RMSNorm + RoPE + scatter ----------
__device__ inline float soft_half(const bf16x8* scv, const bf16x8* kvv,
                                  const float ap[4][8], const bool valid[4], int i) {
  float sc[4];
  #pragma unroll
  for (int r = 0; r < 4; ++r)
    sc[r] = valid[r] ? b2f((u16)scv[r][i]) : -1e30f;
  float m = fmaxf(fmaxf(sc[0], sc[1]), fmaxf(sc[2], sc[3]));
  float e[4], sum = 0.f;
  #pragma unroll
  for (int r = 0; r < 4; ++r) { e[r] = __expf(sc[r] - m); sum += e[r]; }
  float inv = 1.0f / sum;
  float o = 0.f;
  #pragma unroll
  for (int r = 0; r < 4; ++r)
    o += e[r] * (b2f((u16)kvv[r][i]) + ap[r][i]);
  return o * inv;
}

__global__ __launch_bounds__(256) void fuse_kernel(const u16* __restrict__ kvsc,
                                                   const float* __restrict__ ape,
                                                   const float* __restrict__ norm_w,
                                                   const float* __restrict__ cosb,
                                                   const float* __restrict__ sinb,
                                                   const int* __restrict__ bo,
                                                   float* __restrict__ ckv_out,
                                                   float* __restrict__ cache_out) {
  __shared__ float ape_s[4][1024];
  const int t = threadIdx.x;
  for (int j = t; j < 1024; j += 256)
    ((float4*)&ape_s[0][0])[j] = ((const float4*)ape)[j];
  __syncthreads();

  const int wave = t >> 6, lane = t & 63;
  const int g = blockIdx.x * 4 + wave;
  const int b = g >> 12, s = g & 4095;
  const int c0 = lane * 8;

  const u16* base = kvsc + (size_t)b * SLEN * NCOLS;
  bf16x8 kv_lo[4], kv_hi[4], sc_lo[4], sc_hi[4];
  float apl[4][8], aph[4][8];
  bool valid[4];
  #pragma unroll
  for (int r = 0; r < 4; ++r) {
    int sr = s - 3 + r;
    valid[r] = (sr >= 0);
    int src = sr < 0 ? 0 : sr;
    int rot = src & 3;
    const u16* rp = base + (size_t)src * NCOLS;
    kv_lo[r] = *(const bf16x8*)(rp + c0);
    kv_hi[r] = *(const bf16x8*)(rp + 512 + c0);
    sc_lo[r] = *(const bf16x8*)(rp + 1024 + c0);
    sc_hi[r] = *(const bf16x8*)(rp + 1536 + c0);
    *(float4*)&apl[r][0] = *(const float4*)&ape_s[rot][c0];
    *(float4*)&apl[r][4] = *(const float4*)&ape_s[rot][c0 + 4];
    *(float4*)&aph[r][0] = *(const float4*)&ape_s[rot][512 + c0];
    *(float4*)&aph[r][4] = *(const float4*)&ape_s[rot][512 + c0 + 4];
  }

  float res[8];
  float sumsq = 0.f;
  #pragma unroll
  for (int i = 0; i < 8; ++i) {
    float o = soft_half(sc_lo, kv_lo, apl, valid, i) +
              soft_half(sc_hi, kv_hi, aph, valid, i);
    res[i] = o;
    sumsq += o * o;
  }
  #pragma unroll
  for (int off = 32; off > 0; off >>= 1)
    sumsq += __shfl_xor(sumsq, off, 64);
  const float scale = rsqrtf(sumsq * (1.0f / 512.0f) + 1e-6f);

  float4 nwa = *(const float4*)&norm_w[c0];
  float4 nwb = *(const float4*)&norm_w[c0 + 4];
  res[0] *= scale * nwa.x; res[1] *= scale * nwa.y;
  res[2] *= scale * nwa.z; res[3] *= scale * nwa.w;
  res[4] *= scale * nwb.x; res[5] *= scale * nwb.y;
  res[6] *= scale * nwb.z; res[7] *= scale * nwb.w;

  if (lane >= 56) {   // channels 448..511: RoPE
    int j0 = (lane - 56) * 4;
    float4 cs = *(const float4*)&cosb[(size_t)s * 32 + j0];
    float4 sn = *(const float4*)&sinb[(size_t)s * 32 + j0];
    float cc[4] = {cs.x, cs.y, cs.z, cs.w};
    float ss[4] = {sn.x, sn.y, sn.z, sn.w};
    #pragma unroll
    for (int p = 0; p < 4; ++p) {
      float cr = res[2 * p], ci = res[2 * p + 1];
      res[2 * p]     = cr * cc[p] - ci * ss[p];
      res[2 * p + 1] = cr * ss[p] + ci * cc[p];
    }
  }

  float4 v0 = make_float4(res[0], res[1], res[2], res[3]);
  float4 v1 = make_float4(res[4], res[5], res[6], res[7]);
  float* op = ckv_out + (size_t)g * HD + c0;
  *(float4*)op = v0;
  *(float4*)(op + 4) = v1;

  if ((s & 3) == 3) {
    int cidx = s >> 2;
    int blk = bo[b * 16 + (cidx >> 6)];
    int off = cidx & 63;
    float* cp = cache_out + ((size_t)blk * 64 + off) * HD + c0;
    *(float4*)cp = v0;
    *(float4*)(cp + 4) = v1;
  }
}

// ---------- launch ----------
extern "C" void kernel_launch(void* const* d_in, const int* in_sizes, int n_in,
                              void* d_out, int out_size, void* d_ws, size_t ws_size,
                              hipStream_t stream) {
  const float* x    = (const float*)d_in[0];
  const float* wkv  = (const float*)d_in[1];
  const float* wg   = (const float*)d_in[2];
  const float* ape  = (const float*)d_in[3];
  const float* nw   = (const float*)d_in[4];
  const float* cosb = (const float*)d_in[5];
  const float* sinb = (const float*)d_in[6];
  const int*   bo   = (const int*)d_in[7];

  float* out = (float*)d_out;
  char* ws = (char*)d_ws;
  u16* xb   = (u16*)ws;                                              // 128 MiB
  u16* Wt   = (u16*)(ws + (size_t)MROWS * DIMK * 2);                 //  16 MiB
  u16* kvsc = (u16*)(ws + (size_t)MROWS * DIMK * 2 + (size_t)NCOLS * DIMK * 2); // 64 MiB

  hipLaunchKernelGGL(cvt_x_kernel, dim3(32768), dim3(256), 0, stream,
                     (const float4*)x, xb);
  hipLaunchKernelGGL(build_wt_kernel, dim3(32, 64), dim3(256), 0, stream, wkv, wg, Wt);
  hipLaunchKernelGGL(gemm_kernel, dim3(512), dim3(512), 0, stream, xb, Wt, kvsc);

  float* ckv_out = out;
  float* cache_out = out + (size_t)MROWS * HD;
  hipMemsetAsync(cache_out, 0, (size_t)64 * 64 * HD * sizeof(float), stream);
  hipLaunchKernelGGL(fuse_kernel, dim3(MROWS / 4), dim3(256), 0, stream,
                     kvsc, ape, nw, cosb, sinb, bo, ckv_out, cache_out);
}

// Round 7
// 517.506 us; speedup vs baseline: 1.3615x; 1.3615x over previous
//
#include <hip/hip_runtime.h>

// Problem constants (match reference)
#define BATCH 4
#define SLEN  4096
#define DIMK  4096
#define HD    512
#define RD    64
#define NCOLS 2048          // [kv(1024) | sc(1024)]
#define MROWS (BATCH*SLEN)  // 16384

typedef __attribute__((ext_vector_type(8))) short bf16x8;
typedef __attribute__((ext_vector_type(4))) float f32x4;
typedef unsigned short u16;

// ---------- bf16 helpers ----------
__device__ inline u16 f2b(float f) {
  union { float f; unsigned u; } x; x.f = f;
  unsigned r = (x.u + 0x7fffu + ((x.u >> 16) & 1u)) >> 16;
  return (u16)r;
}
__device__ inline float b2f(u16 u) {
  union { float f; unsigned u; } x; x.u = ((unsigned)u) << 16; return x.f;
}

#define GLL16(gp, lp) __builtin_amdgcn_global_load_lds( \
    (__attribute__((address_space(1))) void*)(gp),      \
    (__attribute__((address_space(3))) void*)(lp), 16, 0, 0)

// ---------- kernel 1: x (f32) -> bf16 ----------
__global__ __launch_bounds__(256) void cvt_x_kernel(const float4* __restrict__ x,
                                                    u16* __restrict__ xb) {
  size_t i = (size_t)blockIdx.x * 256 + threadIdx.x;
  float4 a = x[2 * i], b = x[2 * i + 1];
  bf16x8 v;
  v[0] = (short)f2b(a.x); v[1] = (short)f2b(a.y);
  v[2] = (short)f2b(a.z); v[3] = (short)f2b(a.w);
  v[4] = (short)f2b(b.x); v[5] = (short)f2b(b.y);
  v[6] = (short)f2b(b.z); v[7] = (short)f2b(b.w);
  *(bf16x8*)(xb + i * 8) = v;
}

// ---------- kernel 2: Wt[n][k] = [wkv|wgate][k][n] as bf16 ----------
__global__ __launch_bounds__(256) void build_wt_kernel(const float* __restrict__ wkv,
                                                       const float* __restrict__ wg,
                                                       u16* __restrict__ Wt) {
  __shared__ u16 tile[64][72];
  const int n0 = blockIdx.x * 64;
  const int k0 = blockIdx.y * 64;
  const float* src = (n0 < 1024) ? wkv : wg;
  const int nbase = (n0 < 1024) ? n0 : (n0 - 1024);
  const int t = threadIdx.x;
  const int nn = t & 63, kq = t >> 6;
  #pragma unroll
  for (int j = 0; j < 16; ++j) {
    int k = kq + j * 4;
    float v = src[(size_t)(k0 + k) * 1024 + nbase + nn];
    tile[nn][k] = f2b(v);
  }
  __syncthreads();
  const int kk8 = (t & 7) * 8;
  #pragma unroll
  for (int j = 0; j < 2; ++j) {
    int nn2 = (t >> 3) + j * 32;
    bf16x8 v = *(bf16x8*)&tile[nn2][kk8];
    *(bf16x8*)&Wt[(size_t)(n0 + nn2) * DIMK + k0 + kk8] = v;
  }
}

// ---------- kernel 3: GEMM 256x256, BK=64, 4-phase/tile, 1 barrier/phase ----------
// Phase = {STAGE(2 GLL, dead region); reads; lgkmcnt(0); [VMW(8)]; BAR;
// sched_barrier(0); 16 MFMA}. No post-MFMA barrier: a wave's reads are fully
// drained BEFORE it reaches BAR (lgkm0 pre-barrier), and GLL into that region
// is only issued by waves that passed the same BAR -> WAR-safe. After BAR the
// MFMA burst drains WHILE the next phase's stage+reads issue (LDS || MFMA).
// vmcnt ledger identical to R4: VMW(8) at P1/P3, never 0 in-loop.
// LDS [buf][kc][row][8] k-chunk-major: GLL-linear AND conflict-free (meas. 0).
__global__ __launch_bounds__(512, 2) void gemm_kernel(const u16* __restrict__ A,
                                                      const u16* __restrict__ Bt,
                                                      u16* __restrict__ C) {
  __shared__ __align__(16) u16 Asm[2][8][256][8];   // 64 KiB
  __shared__ __align__(16) u16 Bsm[2][8][256][8];   // 64 KiB
  const int t = threadIdx.x;
  const int lane = t & 63, wave = t >> 6;

  // XCD chunked swizzle: nwg=512, 64 contiguous logical blocks per XCD.
  const int orig = blockIdx.x;
  const int lid = (orig & 7) * 64 + (orig >> 3);
  const int mt = lid >> 3, nt = lid & 7;            // nt fast: 8 share A panel
  const int m0 = mt * 256, n0 = nt * 256;
  const int wr = wave >> 2, wc = wave & 3;          // 2M x 4N waves

  f32x4 acc[8][4] = {};

  const int rowS = t & 255, kcS = t >> 8;           // kcS in {0,1}
  const u16* gA = A  + (size_t)(m0 + rowS) * DIMK;
  const u16* gB = Bt + (size_t)(n0 + rowS) * DIMK;

  // Stage one half-tile (2 GLL/thread). kh in {0,1}: k elems kh*32..kh*32+31.
#define SA(buf, tt, kh) do {                                                  \
    GLL16(gA + (tt) * 64 + (kh) * 32 + kcS * 8,                               \
          &Asm[buf][(kh) * 4 + kcS][rowS][0]);                                \
    GLL16(gA + (tt) * 64 + (kh) * 32 + (2 + kcS) * 8,                         \
          &Asm[buf][(kh) * 4 + 2 + kcS][rowS][0]);                            \
  } while (0)
#define SB(buf, tt, kh) do {                                                  \
    GLL16(gB + (tt) * 64 + (kh) * 32 + kcS * 8,                               \
          &Bsm[buf][(kh) * 4 + kcS][rowS][0]);                                \
    GLL16(gB + (tt) * 64 + (kh) * 32 + (2 + kcS) * 8,                         \
          &Bsm[buf][(kh) * 4 + 2 + kcS][rowS][0]);                            \
  } while (0)

#define MFMA16(mb) do {                                                       \
    __builtin_amdgcn_s_setprio(1);                                            \
    _Pragma("unroll")                                                         \
    for (int m = 0; m < 4; ++m) {                                             \
      _Pragma("unroll")                                                       \
      for (int n = 0; n < 4; ++n)                                             \
        acc[(mb) + m][n] = __builtin_amdgcn_mfma_f32_16x16x32_bf16(           \
            af[m], bf[n], acc[(mb) + m][n], 0, 0, 0);                         \
    }                                                                         \
    __builtin_amdgcn_s_setprio(0);                                            \
  } while (0)

#define BARF()  do { asm volatile("s_barrier" ::: "memory");                  \
                     __builtin_amdgcn_sched_barrier(0); } while (0)
#define LKW0()  asm volatile("s_waitcnt lgkmcnt(0)" ::: "memory")
#define VMW(n)  asm volatile("s_waitcnt vmcnt(" #n ")" ::: "memory")

  const int fr = lane & 15, fk = lane >> 4;          // fk in 0..3
  const int NT = DIMK / 64;                          // 64 K-tiles

  // prologue: tile0 (4 halves) + tile1 k0 halves = 12 loads
  SA(0, 0, 0); SB(0, 0, 0); SA(0, 0, 1); SB(0, 0, 1);
  SA(1, 1, 0); SB(1, 1, 0);
  VMW(8);                                            // Ak0(0),Bk0(0) landed
  BARF();

  bf16x8 af[4], bf[4];

  for (int tt = 0; tt < NT; ++tt) {
    const int c = tt & 1;
    const int t1 = (tt + 1 < NT) ? tt + 1 : NT - 1;  // clamped tail (dead buf)
    const int t2 = (tt + 2 < NT) ? tt + 2 : NT - 1;

    // ---- P0: stage A(t1,k1); read kb0 m0-3 + B; MFMA ----
    SA(c ^ 1, t1, 1);
    #pragma unroll
    for (int m = 0; m < 4; ++m)
      af[m] = *(const bf16x8*)&Asm[c][fk][wr * 128 + m * 16 + fr][0];
    #pragma unroll
    for (int n = 0; n < 4; ++n)
      bf[n] = *(const bf16x8*)&Bsm[c][fk][wc * 64 + n * 16 + fr][0];
    LKW0();
    BARF();
    MFMA16(0);

    // ---- P1: stage B(t1,k1); read kb0 m4-7 (bf reused); VMW; MFMA ----
    SB(c ^ 1, t1, 1);
    #pragma unroll
    for (int m = 0; m < 4; ++m)
      af[m] = *(const bf16x8*)&Asm[c][fk][wr * 128 + (m + 4) * 16 + fr][0];
    LKW0();
    VMW(8);                                          // Ak1(tt),Bk1(tt) landed
    BARF();
    MFMA16(4);

    // ---- P2: stage A(t2,k0); read kb1 m0-3 + B; MFMA ----
    SA(c, t2, 0);
    #pragma unroll
    for (int m = 0; m < 4; ++m)
      af[m] = *(const bf16x8*)&Asm[c][4 + fk][wr * 128 + m * 16 + fr][0];
    #pragma unroll
    for (int n = 0; n < 4; ++n)
      bf[n] = *(const bf16x8*)&Bsm[c][4 + fk][wc * 64 + n * 16 + fr][0];
    LKW0();
    BARF();
    MFMA16(0);

    // ---- P3: stage B(t2,k0); read kb1 m4-7; VMW; MFMA ----
    SB(c, t2, 0);
    #pragma unroll
    for (int m = 0; m < 4; ++m)
      af[m] = *(const bf16x8*)&Asm[c][4 + fk][wr * 128 + (m + 4) * 16 + fr][0];
    LKW0();
    VMW(8);                                          // Ak0(tt+1),Bk0(tt+1) landed
    BARF();
    MFMA16(4);
  }
  VMW(0);   // no GLL may land in freed LDS after exit
#undef SA
#undef SB
#undef MFMA16
#undef BARF
#undef LKW0
#undef VMW

  // epilogue: C/D layout col=lane&15, row=(lane>>4)*4+j (m89-verified)
  const int fq = lane >> 4;
  #pragma unroll
  for (int m = 0; m < 8; ++m) {
    #pragma unroll
    for (int n = 0; n < 4; ++n) {
      int col = n0 + wc * 64 + n * 16 + fr;
      int rowb = m0 + wr * 128 + m * 16 + fq * 4;
      #pragma unroll
      for (int j = 0; j < 4; ++j)
        C[(size_t)(rowb + j) * NCOLS + col] = f2b(acc[m][n][j]);
    }
  }
}

// ---------- kernel 4: windowed softmax + halves-sum + RMSNorm + RoPE + scatter ----------
__device__ inline float soft_half(const bf16x8* scv, const bf16x8* kvv,
                                  const float ap[4][8], const bool valid[4], int i) {
  float sc[4];
  #pragma unroll
  for (int r = 0; r < 4; ++r)
    sc[r] = valid[r] ? b2f((u16)scv[r][i]) : -1e30f;
  float m = fmaxf(fmaxf(sc[0], sc[1]), fmaxf(sc[2], sc[3]));
  float e[4], sum = 0.f;
  #pragma unroll
  for (int r = 0; r < 4; ++r) { e[r] = __expf(sc[r] - m); sum += e[r]; }
  float inv = 1.0f / sum;
  float o = 0.f;
  #pragma unroll
  for (int r = 0; r < 4; ++r)
    o += e[r] * (b2f((u16)kvv[r][i]) + ap[r][i]);
  return o * inv;
}

__global__ __launch_bounds__(256) void fuse_kernel(const u16* __restrict__ kvsc,
                                                   const float* __restrict__ ape,
                                                   const float* __restrict__ norm_w,
                                                   const float* __restrict__ cosb,
                                                   const float* __restrict__ sinb,
                                                   const int* __restrict__ bo,
                                                   float* __restrict__ ckv_out,
                                                   float* __restrict__ cache_out) {
  __shared__ float ape_s[4][1024];
  const int t = threadIdx.x;
  for (int j = t; j < 1024; j += 256)
    ((float4*)&ape_s[0][0])[j] = ((const float4*)ape)[j];
  __syncthreads();

  const int wave = t >> 6, lane = t & 63;
  const int g = blockIdx.x * 4 + wave;
  const int b = g >> 12, s = g & 4095;
  const int c0 = lane * 8;

  const u16* base = kvsc + (size_t)b * SLEN * NCOLS;
  bf16x8 kv_lo[4], kv_hi[4], sc_lo[4], sc_hi[4];
  float apl[4][8], aph[4][8];
  bool valid[4];
  #pragma unroll
  for (int r = 0; r < 4; ++r) {
    int sr = s - 3 + r;
    valid[r] = (sr >= 0);
    int src = sr < 0 ? 0 : sr;
    int rot = src & 3;
    const u16* rp = base + (size_t)src * NCOLS;
    kv_lo[r] = *(const bf16x8*)(rp + c0);
    kv_hi[r] = *(const bf16x8*)(rp + 512 + c0);
    sc_lo[r] = *(const bf16x8*)(rp + 1024 + c0);
    sc_hi[r] = *(const bf16x8*)(rp + 1536 + c0);
    *(float4*)&apl[r][0] = *(const float4*)&ape_s[rot][c0];
    *(float4*)&apl[r][4] = *(const float4*)&ape_s[rot][c0 + 4];
    *(float4*)&aph[r][0] = *(const float4*)&ape_s[rot][512 + c0];
    *(float4*)&aph[r][4] = *(const float4*)&ape_s[rot][512 + c0 + 4];
  }

  float res[8];
  float sumsq = 0.f;
  #pragma unroll
  for (int i = 0; i < 8; ++i) {
    float o = soft_half(sc_lo, kv_lo, apl, valid, i) +
              soft_half(sc_hi, kv_hi, aph, valid, i);
    res[i] = o;
    sumsq += o * o;
  }
  #pragma unroll
  for (int off = 32; off > 0; off >>= 1)
    sumsq += __shfl_xor(sumsq, off, 64);
  const float scale = rsqrtf(sumsq * (1.0f / 512.0f) + 1e-6f);

  float4 nwa = *(const float4*)&norm_w[c0];
  float4 nwb = *(const float4*)&norm_w[c0 + 4];
  res[0] *= scale * nwa.x; res[1] *= scale * nwa.y;
  res[2] *= scale * nwa.z; res[3] *= scale * nwa.w;
  res[4] *= scale * nwb.x; res[5] *= scale * nwb.y;
  res[6] *= scale * nwb.z; res[7] *= scale * nwb.w;

  if (lane >= 56) {   // channels 448..511: RoPE
    int j0 = (lane - 56) * 4;
    float4 cs = *(const float4*)&cosb[(size_t)s * 32 + j0];
    float4 sn = *(const float4*)&sinb[(size_t)s * 32 + j0];
    float cc[4] = {cs.x, cs.y, cs.z, cs.w};
    float ss[4] = {sn.x, sn.y, sn.z, sn.w};
    #pragma unroll
    for (int p = 0; p < 4; ++p) {
      float cr = res[2 * p], ci = res[2 * p + 1];
      res[2 * p]     = cr * cc[p] - ci * ss[p];
      res[2 * p + 1] = cr * ss[p] + ci * cc[p];
    }
  }

  float4 v0 = make_float4(res[0], res[1], res[2], res[3]);
  float4 v1 = make_float4(res[4], res[5], res[6], res[7]);
  float* op = ckv_out + (size_t)g * HD + c0;
  *(float4*)op = v0;
  *(float4*)(op + 4) = v1;

  if ((s & 3) == 3) {
    int cidx = s >> 2;
    int blk = bo[b * 16 + (cidx >> 6)];
    int off = cidx & 63;
    float* cp = cache_out + ((size_t)blk * 64 + off) * HD + c0;
    *(float4*)cp = v0;
    *(float4*)(cp + 4) = v1;
  }
}

// ---------- launch ----------
extern "C" void kernel_launch(void* const* d_in, const int* in_sizes, int n_in,
                              void* d_out, int out_size, void* d_ws, size_t ws_size,
                              hipStream_t stream) {
  const float* x    = (const float*)d_in[0];
  const float* wkv  = (const float*)d_in[1];
  const float* wg   = (const float*)d_in[2];
  const float* ape  = (const float*)d_in[3];
  const float* nw   = (const float*)d_in[4];
  const float* cosb = (const float*)d_in[5];
  const float* sinb = (const float*)d_in[6];
  const int*   bo   = (const int*)d_in[7];

  float* out = (float*)d_out;
  char* ws = (char*)d_ws;
  u16* xb   = (u16*)ws;                                              // 128 MiB
  u16* Wt   = (u16*)(ws + (size_t)MROWS * DIMK * 2);                 //  16 MiB
  u16* kvsc = (u16*)(ws + (size_t)MROWS * DIMK * 2 + (size_t)NCOLS * DIMK * 2); // 64 MiB

  hipLaunchKernelGGL(cvt_x_kernel, dim3(32768), dim3(256), 0, stream,
                     (const float4*)x, xb);
  hipLaunchKernelGGL(build_wt_kernel, dim3(32, 64), dim3(256), 0, stream, wkv, wg, Wt);
  hipLaunchKernelGGL(gemm_kernel, dim3(512), dim3(512), 0, stream, xb, Wt, kvsc);

  float* ckv_out = out;
  float* cache_out = out + (size_t)MROWS * HD;
  hipMemsetAsync(cache_out, 0, (size_t)64 * 64 * HD * sizeof(float), stream);
  hipLaunchKernelGGL(fuse_kernel, dim3(MROWS / 4), dim3(256), 0, stream,
                     kvsc, ape, nw, cosb, sinb, bo, ckv_out, cache_out);
}